// Round 7
// baseline (192.733 us; speedup 1.0000x reference)
//
#include <hip/hip_runtime.h>
#include <stdint.h>

#define NN 4096      // nodes
#define EE 131072    // edges
#define IND 1024
#define OUTD 512
#define NH 4
#define NBKT 8       // column buckets for finalize L2 locality (512 nodes = 1MB of fp8 Hb each)
#define BKT_SHIFT 9  // 4096/8 = 512 cols per bucket

typedef __bf16 bf16x8 __attribute__((ext_vector_type(8)));
typedef float f32x4 __attribute__((ext_vector_type(4)));
typedef float f32x2 __attribute__((ext_vector_type(2)));

__device__ __forceinline__ unsigned short f2bf(float f) {
  unsigned u = __float_as_uint(f);
  u += 0x7FFFu + ((u >> 16) & 1u);   // RNE, data has no NaN
  return (unsigned short)(u >> 16);
}

// ---------------- K1: fused prep — cast x -> bf16 (blocks 0..4095), W transpose (4096..6143) ----
__global__ void prep_kernel(const float* __restrict__ x, unsigned short* __restrict__ xb,
                            const float* __restrict__ W, unsigned short* __restrict__ Wt) {
  __shared__ float tile[32][33];
  const int bid = blockIdx.x, t = threadIdx.x;
  if (bid < 4096) {                       // cast x: 4 floats/thread
    int i = bid * 256 + t;
    float4 v = ((const float4*)x)[i];
    ushort4 o;
    o.x = f2bf(v.x); o.y = f2bf(v.y); o.z = f2bf(v.z); o.w = f2bf(v.w);
    ((ushort4*)xb)[i] = o;
  } else {                                // W[h][i][o] f32 -> Wt[h][o][i] bf16
    int b2 = bid - 4096;
    int i0 = (b2 & 31) * 32, o0 = ((b2 >> 5) & 15) * 32, h = b2 >> 9;
    int tx = t & 31, ty = t >> 5;
#pragma unroll
    for (int r = 0; r < 32; r += 8)
      tile[ty + r][tx] = W[((size_t)(h * IND + i0 + ty + r)) * OUTD + o0 + tx];
    __syncthreads();
#pragma unroll
    for (int r = 0; r < 32; r += 8)
      Wt[((size_t)(h * OUTD + o0 + ty + r)) * IND + i0 + tx] = f2bf(tile[tx][ty + r]);
  }
}

// ---------------- K2: bf16 MFMA GEMM 128x128, BK=32, 2-phase dbuf, FUSED epilogue ----------------
// XCD-bijective block swizzle (512 blocks % 8 == 0): blocks sharing an A-panel (same by)
// are contiguous within one XCD's chunk -> A panel re-fetch served by that XCD's L2.
__device__ __forceinline__ void gload16(const unsigned short* g, unsigned short* l) {
  __builtin_amdgcn_global_load_lds((const __attribute__((address_space(1))) void*)g,
                                   (__attribute__((address_space(3))) void*)l, 16, 0, 0);
}

__global__ __launch_bounds__(256, 2) void gemm_kernel(
    const unsigned short* __restrict__ X, const unsigned short* __restrict__ Wt,
    const float* __restrict__ Av, unsigned char* __restrict__ Hb8,
    float* __restrict__ s4_src, float* __restrict__ s4_dst, float* __restrict__ Scol) {
  __shared__ __align__(16) unsigned short As[2][4096];  // [128 rows][32 k] bf16, XOR-swizzled
  __shared__ __align__(16) unsigned short Bs[2][4096];  // [128 n-rows][32 k]
  const int t = threadIdx.x, w = t >> 6, lane = t & 63;
  const int B = blockIdx.x;
  const int L = ((B & 7) << 6) | (B >> 3);   // bijective XCD chunking
  const int bx = L & 3, hh = (L >> 2) & 3, by = L >> 4;

  const unsigned short* Ab0 = X + (size_t)(by * 128) * IND;
  const unsigned short* Bb0 = Wt + (size_t)(hh * OUTD + bx * 128) * IND;

  const int seg0 = w * 64 + lane, seg1 = (4 + w) * 64 + lane;
  const int r0 = seg0 >> 2, c0 = (seg0 & 3) ^ (r0 & 3);
  const int r1 = seg1 >> 2, c1 = (seg1 & 3) ^ (r1 & 3);

  const int wr = w >> 1, wc = w & 1, g = lane >> 4, rlo = lane & 15;
  int aoff[4], boff[4];
#pragma unroll
  for (int i = 0; i < 4; i++) {
    int ra = wr * 64 + i * 16 + rlo;
    aoff[i] = ra * 64 + ((g ^ (ra & 3)) << 4);
    int rb = wc * 64 + i * 16 + rlo;
    boff[i] = rb * 64 + ((g ^ (rb & 3)) << 4);
  }

  f32x4 zero = {0.f, 0.f, 0.f, 0.f};
  f32x4 acc[4][4];
#pragma unroll
  for (int i = 0; i < 4; i++)
#pragma unroll
    for (int j = 0; j < 4; j++) acc[i][j] = zero;

#define STAGE(buf, kt)                                                   \
  do {                                                                   \
    const unsigned short* ga = Ab0 + (kt) * 32;                          \
    const unsigned short* gb = Bb0 + (kt) * 32;                          \
    gload16(ga + r0 * IND + c0 * 8, &As[buf][w * 512]);                  \
    gload16(ga + r1 * IND + c1 * 8, &As[buf][(4 + w) * 512]);            \
    gload16(gb + r0 * IND + c0 * 8, &Bs[buf][w * 512]);                  \
    gload16(gb + r1 * IND + c1 * 8, &Bs[buf][(4 + w) * 512]);            \
  } while (0)

  STAGE(0, 0);
  __syncthreads();
  int cur = 0;
  for (int kt = 0; kt < 32; ++kt) {
    if (kt != 31) STAGE(cur ^ 1, kt + 1);
    const char* Abuf = (const char*)As[cur];
    const char* Bbuf = (const char*)Bs[cur];
    bf16x8 av[4], bv[4];
#pragma unroll
    for (int i = 0; i < 4; i++) {
      av[i] = *(const bf16x8*)(Abuf + aoff[i]);
      bv[i] = *(const bf16x8*)(Bbuf + boff[i]);
    }
#pragma unroll
    for (int i = 0; i < 4; i++)
#pragma unroll
      for (int j = 0; j < 4; j++)
        acc[i][j] = __builtin_amdgcn_mfma_f32_16x16x32_bf16(av[i], bv[j], acc[i][j], 0, 0, 0);
    __syncthreads();
    cur ^= 1;
  }
#undef STAGE

  // ---- epilogue. C/D layout: col = lane&15 (rlo), row = (lane>>4)*4+q  [m89/m91 verified]
#pragma unroll
  for (int i = 0; i < 4; i++)
#pragma unroll
    for (int j = 0; j < 4; j++) {
      int mm0 = by * 128 + wr * 64 + i * 16 + g * 4;
      int nn = bx * 128 + wc * 64 + j * 16 + rlo;
#pragma unroll
      for (int q = 0; q < 4; q++) {
        int p = __builtin_amdgcn_cvt_pk_fp8_f32(acc[i][j][q], acc[i][j][q], 0, false);
        Hb8[((size_t)(mm0 + q) * NH + hh) * OUTD + nn] = (unsigned char)p;
      }
    }

  float as_[4], ad_[4];
#pragma unroll
  for (int j = 0; j < 4; j++) {
    int nn = bx * 128 + wc * 64 + j * 16 + rlo;
    as_[j] = Av[hh * 2 * OUTD + nn];
    ad_[j] = Av[hh * 2 * OUTD + OUTD + nn];
  }
#pragma unroll
  for (int i = 0; i < 4; i++)
#pragma unroll
    for (int q = 0; q < 4; q++) {
      float vs = 0.f, vd = 0.f;
#pragma unroll
      for (int j = 0; j < 4; j++) {
        float tv = acc[i][j][q];
        vs += tv * as_[j];
        vd += tv * ad_[j];
      }
#pragma unroll
      for (int m = 1; m < 16; m <<= 1) {
        vs += __shfl_xor(vs, m);
        vd += __shfl_xor(vd, m);
      }
      if (rlo == 0) {
        int r = by * 128 + wr * 64 + i * 16 + g * 4 + q;
        atomicAdd(&s4_src[r * NH + hh], vs);   // [node][head] layout for edge_b float4 loads
        atomicAdd(&s4_dst[r * NH + hh], vd);
      }
    }

#pragma unroll
  for (int j = 0; j < 4; j++) {
    float cv = 0.f;
#pragma unroll
    for (int i = 0; i < 4; i++)
#pragma unroll
      for (int q = 0; q < 4; q++) cv += acc[i][j][q];
    cv += __shfl_xor(cv, 16);
    cv += __shfl_xor(cv, 32);
    if (g == 0) {
      int nn = bx * 128 + wc * 64 + j * 16 + rlo;
      atomicAdd(&Scol[hh * OUTD + nn], cv);
    }
  }
}

// ---------------- K4: edge pass A — dedup + per-(row,bucket) counts only ----------------
__global__ void edge_a_kernel(const int* __restrict__ ei, unsigned* __restrict__ bitmap,
                              int* __restrict__ counts2, unsigned char* __restrict__ flags) {
  int e = blockIdx.x * 256 + threadIdx.x;
  int row = ei[e], col = ei[EE + e];
  unsigned key = ((unsigned)row << 12) | (unsigned)col;
  unsigned bit = 1u << (key & 31);
  unsigned old = atomicOr(&bitmap[key >> 5], bit);
  if (old & bit) { flags[e] = 1; return; }   // duplicate (same e value -> any winner ok)
  flags[e] = 0;
  atomicAdd(&counts2[row * NBKT + (col >> BKT_SHIFT)], 1);
}

// ---------------- K5: single-block exclusive scan of counts2 (32768 = 1024 thr x 32) --------
__global__ __launch_bounds__(1024) void scan_kernel(const int* __restrict__ c2,
                                                    int* __restrict__ off2,
                                                    int* __restrict__ cur2) {
  __shared__ int wtot[16];
  const int t = threadIdx.x, w = t >> 6, lane = t & 63;
  int loc[32];
  const int4* src = (const int4*)c2 + t * 8;
#pragma unroll
  for (int k = 0; k < 8; k++) {
    int4 v = src[k];
    loc[4 * k] = v.x; loc[4 * k + 1] = v.y; loc[4 * k + 2] = v.z; loc[4 * k + 3] = v.w;
  }
  int s = 0;
#pragma unroll
  for (int k = 0; k < 32; k++) s += loc[k];
  int inc = s;
#pragma unroll
  for (int d = 1; d < 64; d <<= 1) {
    int u = __shfl_up(inc, d);
    if (lane >= d) inc += u;
  }
  if (lane == 63) wtot[w] = inc;
  __syncthreads();
  int wpre = 0;
  for (int k = 0; k < 16; k++)
    if (k < w) wpre += wtot[k];
  int o = wpre + inc - s;   // exclusive prefix for this thread's chunk
  if (t == 1023) off2[NN * NBKT] = o + s;   // sentinel: total nondup count
  int4* od = (int4*)off2 + t * 8;
  int4* cd = (int4*)cur2 + t * 8;
#pragma unroll
  for (int k = 0; k < 8; k++) {
    int4 ov;
    ov.x = o; o += loc[4 * k];
    ov.y = o; o += loc[4 * k + 1];
    ov.z = o; o += loc[4 * k + 2];
    ov.w = o; o += loc[4 * k + 3];
    od[k] = ov;
    cd[k] = ov;
  }
}

// ---------------- K6: edge pass B — bucketed CSR scatter + g coeffs ----------------
__global__ void edge_b_kernel(const int* __restrict__ ei, const unsigned char* __restrict__ flags,
                              const float* __restrict__ s4_src, const float* __restrict__ s4_dst,
                              int* __restrict__ cursor2, int* __restrict__ csr_col,
                              float* __restrict__ csr_g4) {
  int e = blockIdx.x * 256 + threadIdx.x;
  if (flags[e]) return;
  int row = ei[e], col = ei[EE + e];
  int pos = atomicAdd(&cursor2[row * NBKT + (col >> BKT_SHIFT)], 1);
  csr_col[pos] = col;
  float4 ss = *(const float4*)(s4_src + row * NH);
  float4 sd = *(const float4*)(s4_dst + col * NH);
  float4 gv;
  float e0 = ss.x + sd.x; e0 = e0 > 0.f ? e0 : 0.2f * e0; gv.x = expf(e0) - 1.0f;
  float e1 = ss.y + sd.y; e1 = e1 > 0.f ? e1 : 0.2f * e1; gv.y = expf(e1) - 1.0f;
  float e2 = ss.z + sd.z; e2 = e2 > 0.f ? e2 : 0.2f * e2; gv.z = expf(e2) - 1.0f;
  float e3 = ss.w + sd.w; e3 = e3 > 0.f ? e3 : 0.2f * e3; gv.w = expf(e3) - 1.0f;
  *(float4*)(csr_g4 + (size_t)pos * NH) = gv;
}

// ---------------- K7: finalize — wave w = head w; fp8 gather; D accumulated locally ----------
__global__ __launch_bounds__(256) void finalize_kernel(
    const unsigned char* __restrict__ Hb8,   // [node][head][out] fp8 e4m3
    const float* __restrict__ S, const int* __restrict__ offsets2,
    const int* __restrict__ csr_col, const float* __restrict__ csr_g4,
    float* __restrict__ out) {
  __shared__ int cols_s[64];
  __shared__ float g_s[4][64];
  const int i = blockIdx.x, t = threadIdx.x;
  const int w = t >> 6, lane = t & 63;   // wave w handles head w

  float acc[8];
  {
    const float4* Sv = (const float4*)(S + w * OUTD + lane * 8);
    float4 s0 = Sv[0], s1 = Sv[1];
    acc[0] = s0.x; acc[1] = s0.y; acc[2] = s0.z; acc[3] = s0.w;
    acc[4] = s1.x; acc[5] = s1.y; acc[6] = s1.z; acc[7] = s1.w;
  }
  float gsum = 0.f;

  const int start = offsets2[i * NBKT];
  const int cnt = offsets2[(i + 1) * NBKT] - start;   // i=4095 hits the sentinel
  for (int base = 0; base < cnt; base += 64) {
    int nload = min(64, cnt - base);
    __syncthreads();
    if (w == 0) cols_s[lane] = (lane < nload) ? csr_col[start + base + lane] : 0;
    {
      int el = t >> 2;   // cooperative coalesced stage: 256 f32 = 64 edges x 4 heads
      float gvv = (el < nload) ? csr_g4[(size_t)(start + base) * NH + t] : 0.f;
      g_s[t & 3][el] = gvv;
    }
    __syncthreads();
#pragma unroll 4
    for (int k = 0; k < nload; k++) {
      int cc = cols_s[k];
      float gg = g_s[w][k];
      gsum += gg;
      uint2 u = *(const uint2*)(Hb8 + ((size_t)(cc * NH + w)) * OUTD + lane * 8);
      f32x2 p0 = __builtin_amdgcn_cvt_pk_f32_fp8(u.x, false);
      f32x2 p1 = __builtin_amdgcn_cvt_pk_f32_fp8(u.x, true);
      f32x2 p2 = __builtin_amdgcn_cvt_pk_f32_fp8(u.y, false);
      f32x2 p3 = __builtin_amdgcn_cvt_pk_f32_fp8(u.y, true);
      acc[0] += gg * p0[0];
      acc[1] += gg * p0[1];
      acc[2] += gg * p1[0];
      acc[3] += gg * p1[1];
      acc[4] += gg * p2[0];
      acc[5] += gg * p2[1];
      acc[6] += gg * p3[0];
      acc[7] += gg * p3[1];
    }
  }

  float inv = 1.0f / ((float)NN + gsum);   // D = N*exp(0) + sum(exp(e)-1); max-shift unnecessary
  float4 o0, o1;
  o0.x = acc[0] * inv; o0.y = acc[1] * inv; o0.z = acc[2] * inv; o0.w = acc[3] * inv;
  o1.x = acc[4] * inv; o1.y = acc[5] * inv; o1.z = acc[6] * inv; o1.w = acc[7] * inv;
  float* ob = out + (size_t)i * (NH * OUTD) + w * OUTD + lane * 8;
  ((float4*)ob)[0] = o0;
  ((float4*)ob)[1] = o1;
}

extern "C" void kernel_launch(void* const* d_in, const int* in_sizes, int n_in,
                              void* d_out, int out_size, void* d_ws, size_t ws_size,
                              hipStream_t stream) {
  const float* x = (const float*)d_in[0];
  const int* ei = (const int*)d_in[1];
  const float* W = (const float*)d_in[2];
  const float* a = (const float*)d_in[3];
  float* out = (float*)d_out;

  char* ws = (char*)d_ws;
  unsigned short* xb = (unsigned short*)(ws);                       // 8 MB
  unsigned short* wt = (unsigned short*)(ws + (8ull << 20));        // 4 MB
  unsigned char* Hb8 = (unsigned char*)(ws + (12ull << 20));        // 8 MB  [node][head][out] fp8
  // ---- single contiguous zeroed region: s4_src, s4_dst, Scol, counts2, bitmap ----
  char* zreg = ws + (20ull << 20);
  float* s4_src = (float*)(zreg);                                   // 64 KB [node][head]
  float* s4_dst = (float*)(zreg + 65536);                           // 64 KB [node][head]
  float* Scol = (float*)(zreg + 2 * 65536);                         // 8 KB
  int* counts2 = (int*)(zreg + 2 * 65536 + 8192);                   // 128 KB
  unsigned* bitmap = (unsigned*)(zreg + 2 * 65536 + 8192 + 131072); // 2 MB
  const size_t ZBYTES = 2 * 65536 + 8192 + 131072 + ((size_t)NN * NN / 8);
  // ---- non-zeroed scratch ----
  unsigned char* flags = (unsigned char*)(ws + (23ull << 20));      // 128 KB
  int* offsets2 = (int*)(ws + (23ull << 20) + 262144);              // 128 KB + 4 (sentinel)
  int* cursor2 = (int*)(ws + (23ull << 20) + 2 * 262144);           // 128 KB
  int* csr_col = (int*)(ws + (24ull << 20));                        // 512 KB
  float* csr_g4 = (float*)(ws + (25ull << 20));                     // 2 MB [edge][head] (27 MB)

  hipMemsetAsync(zreg, 0, ZBYTES, stream);

  prep_kernel<<<4096 + 2048, 256, 0, stream>>>(x, xb, W, wt);
  gemm_kernel<<<512, 256, 0, stream>>>(xb, wt, a, Hb8, s4_src, s4_dst, Scol);
  edge_a_kernel<<<EE / 256, 256, 0, stream>>>(ei, bitmap, counts2, flags);
  scan_kernel<<<1, 1024, 0, stream>>>(counts2, offsets2, cursor2);
  edge_b_kernel<<<EE / 256, 256, 0, stream>>>(ei, flags, s4_src, s4_dst, cursor2, csr_col,
                                              csr_g4);
  finalize_kernel<<<NN, 256, 0, stream>>>(Hb8, Scol, offsets2, csr_col, csr_g4, out);
}

// Round 8
// 185.047 us; speedup vs baseline: 1.0415x; 1.0415x over previous
//
#include <hip/hip_runtime.h>
#include <stdint.h>

#define NN 4096      // nodes
#define EE 131072    // edges
#define IND 1024
#define OUTD 512
#define NH 4
#define NBKT 8       // column buckets for finalize L2 locality (512 nodes = 1MB of fp8 Hb each)
#define BKT_SHIFT 9  // 4096/8 = 512 cols per bucket

typedef __bf16 bf16x8 __attribute__((ext_vector_type(8)));
typedef float f32x4 __attribute__((ext_vector_type(4)));
typedef float f32x2 __attribute__((ext_vector_type(2)));

__device__ __forceinline__ unsigned short f2bf(float f) {
  unsigned u = __float_as_uint(f);
  u += 0x7FFFu + ((u >> 16) & 1u);   // RNE, data has no NaN
  return (unsigned short)(u >> 16);
}

// ---------------- K1: fused prep — cast x -> bf16 (blocks 0..4095), W transpose (4096..6143) ----
__global__ void prep_kernel(const float* __restrict__ x, unsigned short* __restrict__ xb,
                            const float* __restrict__ W, unsigned short* __restrict__ Wt) {
  __shared__ float tile[32][33];
  const int bid = blockIdx.x, t = threadIdx.x;
  if (bid < 4096) {                       // cast x: 4 floats/thread
    int i = bid * 256 + t;
    float4 v = ((const float4*)x)[i];
    ushort4 o;
    o.x = f2bf(v.x); o.y = f2bf(v.y); o.z = f2bf(v.z); o.w = f2bf(v.w);
    ((ushort4*)xb)[i] = o;
  } else {                                // W[h][i][o] f32 -> Wt[h][o][i] bf16
    int b2 = bid - 4096;
    int i0 = (b2 & 31) * 32, o0 = ((b2 >> 5) & 15) * 32, h = b2 >> 9;
    int tx = t & 31, ty = t >> 5;
#pragma unroll
    for (int r = 0; r < 32; r += 8)
      tile[ty + r][tx] = W[((size_t)(h * IND + i0 + ty + r)) * OUTD + o0 + tx];
    __syncthreads();
#pragma unroll
    for (int r = 0; r < 32; r += 8)
      Wt[((size_t)(h * OUTD + o0 + ty + r)) * IND + i0 + tx] = f2bf(tile[tx][ty + r]);
  }
}

// ---------------- K2: bf16 MFMA GEMM 128x128, BK=64, 2-phase dbuf, FUSED epilogue ----------------
// LDS rows are 128B (one full bank wrap); both-sides XOR swizzle f(r)=r&7 gives 2-way
// (free) bank aliasing on ds_read_b128. 16 K-iterations (half the barrier drains of BK=32).
__device__ __forceinline__ void gload16(const unsigned short* g, unsigned short* l) {
  __builtin_amdgcn_global_load_lds((const __attribute__((address_space(1))) void*)g,
                                   (__attribute__((address_space(3))) void*)l, 16, 0, 0);
}

__global__ __launch_bounds__(256, 2) void gemm_kernel(
    const unsigned short* __restrict__ X, const unsigned short* __restrict__ Wt,
    const float* __restrict__ Av, unsigned char* __restrict__ Hb8,
    float* __restrict__ s4_src, float* __restrict__ s4_dst, float* __restrict__ Scol) {
  __shared__ __align__(16) unsigned short As[2][8192];  // [128 rows][64 k] bf16, XOR-swizzled
  __shared__ __align__(16) unsigned short Bs[2][8192];  // [128 n-rows][64 k]
  const int t = threadIdx.x, w = t >> 6, lane = t & 63;
  const int bx = blockIdx.x & 3, hh = (blockIdx.x >> 2) & 3, by = blockIdx.x >> 4;

  const unsigned short* Ab0 = X + (size_t)(by * 128) * IND;
  const unsigned short* Bb0 = Wt + (size_t)(hh * OUTD + bx * 128) * IND;

  // staging: 1024 granules (16B) per tile; seg -> row=seg>>3, col-granule=(seg&7)^(row&7)
  int srowA[4], scgA[4];
#pragma unroll
  for (int k = 0; k < 4; k++) {
    int seg = w * 64 + k * 256 + lane;
    srowA[k] = seg >> 3;
    scgA[k] = (seg & 7) ^ (srowA[k] & 7);
  }

  // fragment read byte offsets: lane (rlo,g) reads row ra, k-slice (ki*4+g)
  const int wr = w >> 1, wc = w & 1, g = lane >> 4, rlo = lane & 15;
  int aoff[4][2], boff[4][2];
#pragma unroll
  for (int i = 0; i < 4; i++)
#pragma unroll
    for (int ki = 0; ki < 2; ki++) {
      int ra = wr * 64 + i * 16 + rlo;
      aoff[i][ki] = ra * 128 + (((ki * 4 + g) ^ (ra & 7)) << 4);
      int rb = wc * 64 + i * 16 + rlo;
      boff[i][ki] = rb * 128 + (((ki * 4 + g) ^ (rb & 7)) << 4);
    }

  f32x4 zero = {0.f, 0.f, 0.f, 0.f};
  f32x4 acc[4][4];
#pragma unroll
  for (int i = 0; i < 4; i++)
#pragma unroll
    for (int j = 0; j < 4; j++) acc[i][j] = zero;

#define STAGE(buf, kt)                                                       \
  do {                                                                       \
    const unsigned short* ga = Ab0 + (kt) * 64;                              \
    const unsigned short* gb = Bb0 + (kt) * 64;                              \
    _Pragma("unroll") for (int k = 0; k < 4; k++) {                          \
      gload16(ga + srowA[k] * IND + scgA[k] * 8, &As[buf][(w * 64 + k * 256) * 8]); \
      gload16(gb + srowA[k] * IND + scgA[k] * 8, &Bs[buf][(w * 64 + k * 256) * 8]); \
    }                                                                        \
  } while (0)

  STAGE(0, 0);
  __syncthreads();
  int cur = 0;
  for (int kt = 0; kt < 16; ++kt) {
    if (kt != 15) STAGE(cur ^ 1, kt + 1);
    const char* Abuf = (const char*)As[cur];
    const char* Bbuf = (const char*)Bs[cur];
    bf16x8 av[4][2], bv[4][2];
#pragma unroll
    for (int i = 0; i < 4; i++)
#pragma unroll
      for (int ki = 0; ki < 2; ki++) {
        av[i][ki] = *(const bf16x8*)(Abuf + aoff[i][ki]);
        bv[i][ki] = *(const bf16x8*)(Bbuf + boff[i][ki]);
      }
#pragma unroll
    for (int ki = 0; ki < 2; ki++)
#pragma unroll
      for (int i = 0; i < 4; i++)
#pragma unroll
        for (int j = 0; j < 4; j++)
          acc[i][j] =
              __builtin_amdgcn_mfma_f32_16x16x32_bf16(av[i][ki], bv[j][ki], acc[i][j], 0, 0, 0);
    __syncthreads();
    cur ^= 1;
  }
#undef STAGE

  // ---- epilogue. C/D layout: col = lane&15 (rlo), row = (lane>>4)*4+q  [m89/m91 verified]
#pragma unroll
  for (int i = 0; i < 4; i++)
#pragma unroll
    for (int j = 0; j < 4; j++) {
      int mm0 = by * 128 + wr * 64 + i * 16 + g * 4;
      int nn = bx * 128 + wc * 64 + j * 16 + rlo;
#pragma unroll
      for (int q = 0; q < 4; q++) {
        int p = __builtin_amdgcn_cvt_pk_fp8_f32(acc[i][j][q], acc[i][j][q], 0, false);
        Hb8[((size_t)(mm0 + q) * NH + hh) * OUTD + nn] = (unsigned char)p;
      }
    }

  float as_[4], ad_[4];
#pragma unroll
  for (int j = 0; j < 4; j++) {
    int nn = bx * 128 + wc * 64 + j * 16 + rlo;
    as_[j] = Av[hh * 2 * OUTD + nn];
    ad_[j] = Av[hh * 2 * OUTD + OUTD + nn];
  }
#pragma unroll
  for (int i = 0; i < 4; i++)
#pragma unroll
    for (int q = 0; q < 4; q++) {
      float vs = 0.f, vd = 0.f;
#pragma unroll
      for (int j = 0; j < 4; j++) {
        float tv = acc[i][j][q];
        vs += tv * as_[j];
        vd += tv * ad_[j];
      }
#pragma unroll
      for (int m = 1; m < 16; m <<= 1) {
        vs += __shfl_xor(vs, m);
        vd += __shfl_xor(vd, m);
      }
      if (rlo == 0) {
        int r = by * 128 + wr * 64 + i * 16 + g * 4 + q;
        atomicAdd(&s4_src[r * NH + hh], vs);   // [node][head] layout for edge_b float4 loads
        atomicAdd(&s4_dst[r * NH + hh], vd);
      }
    }

#pragma unroll
  for (int j = 0; j < 4; j++) {
    float cv = 0.f;
#pragma unroll
    for (int i = 0; i < 4; i++)
#pragma unroll
      for (int q = 0; q < 4; q++) cv += acc[i][j][q];
    cv += __shfl_xor(cv, 16);
    cv += __shfl_xor(cv, 32);
    if (g == 0) {
      int nn = bx * 128 + wc * 64 + j * 16 + rlo;
      atomicAdd(&Scol[hh * OUTD + nn], cv);
    }
  }
}

// ---------------- K4: edge pass A — dedup + per-(row,bucket) counts only ----------------
__global__ void edge_a_kernel(const int* __restrict__ ei, unsigned* __restrict__ bitmap,
                              int* __restrict__ counts2, unsigned char* __restrict__ flags) {
  int e = blockIdx.x * 256 + threadIdx.x;
  int row = ei[e], col = ei[EE + e];
  unsigned key = ((unsigned)row << 12) | (unsigned)col;
  unsigned bit = 1u << (key & 31);
  unsigned old = atomicOr(&bitmap[key >> 5], bit);
  if (old & bit) { flags[e] = 1; return; }   // duplicate (same e value -> any winner ok)
  flags[e] = 0;
  atomicAdd(&counts2[row * NBKT + (col >> BKT_SHIFT)], 1);
}

// ---------------- K5: single-block exclusive scan of counts2 (32768 = 1024 thr x 32) --------
__global__ __launch_bounds__(1024) void scan_kernel(const int* __restrict__ c2,
                                                    int* __restrict__ off2,
                                                    int* __restrict__ cur2) {
  __shared__ int wtot[16];
  const int t = threadIdx.x, w = t >> 6, lane = t & 63;
  int loc[32];
  const int4* src = (const int4*)c2 + t * 8;
#pragma unroll
  for (int k = 0; k < 8; k++) {
    int4 v = src[k];
    loc[4 * k] = v.x; loc[4 * k + 1] = v.y; loc[4 * k + 2] = v.z; loc[4 * k + 3] = v.w;
  }
  int s = 0;
#pragma unroll
  for (int k = 0; k < 32; k++) s += loc[k];
  int inc = s;
#pragma unroll
  for (int d = 1; d < 64; d <<= 1) {
    int u = __shfl_up(inc, d);
    if (lane >= d) inc += u;
  }
  if (lane == 63) wtot[w] = inc;
  __syncthreads();
  int wpre = 0;
  for (int k = 0; k < 16; k++)
    if (k < w) wpre += wtot[k];
  int o = wpre + inc - s;   // exclusive prefix for this thread's chunk
  if (t == 1023) off2[NN * NBKT] = o + s;   // sentinel: total nondup count
  int4* od = (int4*)off2 + t * 8;
  int4* cd = (int4*)cur2 + t * 8;
#pragma unroll
  for (int k = 0; k < 8; k++) {
    int4 ov;
    ov.x = o; o += loc[4 * k];
    ov.y = o; o += loc[4 * k + 1];
    ov.z = o; o += loc[4 * k + 2];
    ov.w = o; o += loc[4 * k + 3];
    od[k] = ov;
    cd[k] = ov;
  }
}

// ---------------- K6: edge pass B — bucketed CSR scatter + g coeffs ----------------
__global__ void edge_b_kernel(const int* __restrict__ ei, const unsigned char* __restrict__ flags,
                              const float* __restrict__ s4_src, const float* __restrict__ s4_dst,
                              int* __restrict__ cursor2, int* __restrict__ csr_col,
                              float* __restrict__ csr_g4) {
  int e = blockIdx.x * 256 + threadIdx.x;
  if (flags[e]) return;
  int row = ei[e], col = ei[EE + e];
  int pos = atomicAdd(&cursor2[row * NBKT + (col >> BKT_SHIFT)], 1);
  csr_col[pos] = col;
  float4 ss = *(const float4*)(s4_src + row * NH);
  float4 sd = *(const float4*)(s4_dst + col * NH);
  float4 gv;
  float e0 = ss.x + sd.x; e0 = e0 > 0.f ? e0 : 0.2f * e0; gv.x = expf(e0) - 1.0f;
  float e1 = ss.y + sd.y; e1 = e1 > 0.f ? e1 : 0.2f * e1; gv.y = expf(e1) - 1.0f;
  float e2 = ss.z + sd.z; e2 = e2 > 0.f ? e2 : 0.2f * e2; gv.z = expf(e2) - 1.0f;
  float e3 = ss.w + sd.w; e3 = e3 > 0.f ? e3 : 0.2f * e3; gv.w = expf(e3) - 1.0f;
  *(float4*)(csr_g4 + (size_t)pos * NH) = gv;
}

// ---------------- K7: finalize — wave w = head w; fp8 gather; D accumulated locally ----------
__global__ __launch_bounds__(256) void finalize_kernel(
    const unsigned char* __restrict__ Hb8,   // [node][head][out] fp8 e4m3
    const float* __restrict__ S, const int* __restrict__ offsets2,
    const int* __restrict__ csr_col, const float* __restrict__ csr_g4,
    float* __restrict__ out) {
  __shared__ int cols_s[64];
  __shared__ float g_s[4][64];
  const int i = blockIdx.x, t = threadIdx.x;
  const int w = t >> 6, lane = t & 63;   // wave w handles head w

  float acc[8];
  {
    const float4* Sv = (const float4*)(S + w * OUTD + lane * 8);
    float4 s0 = Sv[0], s1 = Sv[1];
    acc[0] = s0.x; acc[1] = s0.y; acc[2] = s0.z; acc[3] = s0.w;
    acc[4] = s1.x; acc[5] = s1.y; acc[6] = s1.z; acc[7] = s1.w;
  }
  float gsum = 0.f;

  const int start = offsets2[i * NBKT];
  const int cnt = offsets2[(i + 1) * NBKT] - start;   // i=4095 hits the sentinel
  for (int base = 0; base < cnt; base += 64) {
    int nload = min(64, cnt - base);
    __syncthreads();
    if (w == 0) cols_s[lane] = (lane < nload) ? csr_col[start + base + lane] : 0;
    {
      int el = t >> 2;   // cooperative coalesced stage: 256 f32 = 64 edges x 4 heads
      float gvv = (el < nload) ? csr_g4[(size_t)(start + base) * NH + t] : 0.f;
      g_s[t & 3][el] = gvv;
    }
    __syncthreads();
#pragma unroll 4
    for (int k = 0; k < nload; k++) {
      int cc = cols_s[k];
      float gg = g_s[w][k];
      gsum += gg;
      uint2 u = *(const uint2*)(Hb8 + ((size_t)(cc * NH + w)) * OUTD + lane * 8);
      f32x2 p0 = __builtin_amdgcn_cvt_pk_f32_fp8(u.x, false);
      f32x2 p1 = __builtin_amdgcn_cvt_pk_f32_fp8(u.x, true);
      f32x2 p2 = __builtin_amdgcn_cvt_pk_f32_fp8(u.y, false);
      f32x2 p3 = __builtin_amdgcn_cvt_pk_f32_fp8(u.y, true);
      acc[0] += gg * p0[0];
      acc[1] += gg * p0[1];
      acc[2] += gg * p1[0];
      acc[3] += gg * p1[1];
      acc[4] += gg * p2[0];
      acc[5] += gg * p2[1];
      acc[6] += gg * p3[0];
      acc[7] += gg * p3[1];
    }
  }

  float inv = 1.0f / ((float)NN + gsum);   // D = N*exp(0) + sum(exp(e)-1); max-shift unnecessary
  float4 o0, o1;
  o0.x = acc[0] * inv; o0.y = acc[1] * inv; o0.z = acc[2] * inv; o0.w = acc[3] * inv;
  o1.x = acc[4] * inv; o1.y = acc[5] * inv; o1.z = acc[6] * inv; o1.w = acc[7] * inv;
  float* ob = out + (size_t)i * (NH * OUTD) + w * OUTD + lane * 8;
  ((float4*)ob)[0] = o0;
  ((float4*)ob)[1] = o1;
}

extern "C" void kernel_launch(void* const* d_in, const int* in_sizes, int n_in,
                              void* d_out, int out_size, void* d_ws, size_t ws_size,
                              hipStream_t stream) {
  const float* x = (const float*)d_in[0];
  const int* ei = (const int*)d_in[1];
  const float* W = (const float*)d_in[2];
  const float* a = (const float*)d_in[3];
  float* out = (float*)d_out;

  char* ws = (char*)d_ws;
  unsigned short* xb = (unsigned short*)(ws);                       // 8 MB
  unsigned short* wt = (unsigned short*)(ws + (8ull << 20));        // 4 MB
  unsigned char* Hb8 = (unsigned char*)(ws + (12ull << 20));        // 8 MB  [node][head][out] fp8
  // ---- single contiguous zeroed region: s4_src, s4_dst, Scol, counts2, bitmap ----
  char* zreg = ws + (20ull << 20);
  float* s4_src = (float*)(zreg);                                   // 64 KB [node][head]
  float* s4_dst = (float*)(zreg + 65536);                           // 64 KB [node][head]
  float* Scol = (float*)(zreg + 2 * 65536);                         // 8 KB
  int* counts2 = (int*)(zreg + 2 * 65536 + 8192);                   // 128 KB
  unsigned* bitmap = (unsigned*)(zreg + 2 * 65536 + 8192 + 131072); // 2 MB
  const size_t ZBYTES = 2 * 65536 + 8192 + 131072 + ((size_t)NN * NN / 8);
  // ---- non-zeroed scratch ----
  unsigned char* flags = (unsigned char*)(ws + (23ull << 20));      // 128 KB
  int* offsets2 = (int*)(ws + (23ull << 20) + 262144);              // 128 KB + 4 (sentinel)
  int* cursor2 = (int*)(ws + (23ull << 20) + 2 * 262144);           // 128 KB
  int* csr_col = (int*)(ws + (24ull << 20));                        // 512 KB
  float* csr_g4 = (float*)(ws + (25ull << 20));                     // 2 MB [edge][head] (27 MB)

  hipMemsetAsync(zreg, 0, ZBYTES, stream);

  prep_kernel<<<4096 + 2048, 256, 0, stream>>>(x, xb, W, wt);
  gemm_kernel<<<512, 256, 0, stream>>>(xb, wt, a, Hb8, s4_src, s4_dst, Scol);
  edge_a_kernel<<<EE / 256, 256, 0, stream>>>(ei, bitmap, counts2, flags);
  scan_kernel<<<1, 1024, 0, stream>>>(counts2, offsets2, cursor2);
  edge_b_kernel<<<EE / 256, 256, 0, stream>>>(ei, flags, s4_src, s4_dst, cursor2, csr_col,
                                              csr_g4);
  finalize_kernel<<<NN, 256, 0, stream>>>(Hb8, Scol, offsets2, csr_col, csr_g4, out);
}

// Round 9
// 182.523 us; speedup vs baseline: 1.0559x; 1.0138x over previous
//
#include <hip/hip_runtime.h>
#include <stdint.h>

#define NN 4096      // nodes
#define EE 131072    // edges
#define IND 1024
#define OUTD 512
#define NH 4
#define NBKT 8       // column buckets for finalize L2 locality (512 nodes = 1MB of fp8 Hb each)
#define BKT_SHIFT 9  // 4096/8 = 512 cols per bucket

typedef __bf16 bf16x8 __attribute__((ext_vector_type(8)));
typedef float f32x4 __attribute__((ext_vector_type(4)));
typedef float f32x2 __attribute__((ext_vector_type(2)));

__device__ __forceinline__ unsigned short f2bf(float f) {
  unsigned u = __float_as_uint(f);
  u += 0x7FFFu + ((u >> 16) & 1u);   // RNE, data has no NaN
  return (unsigned short)(u >> 16);
}

// ---------------- K1: fused prep — x cast (0..4095) | W transpose (4096..6143) | edge_a (6144+) --
__global__ void prep_edge_kernel(const float* __restrict__ x, unsigned short* __restrict__ xb,
                                 const float* __restrict__ W, unsigned short* __restrict__ Wt,
                                 const int* __restrict__ ei, unsigned* __restrict__ bitmap,
                                 int* __restrict__ counts2, unsigned char* __restrict__ flags) {
  __shared__ float tile[32][33];
  const int bid = blockIdx.x, t = threadIdx.x;
  if (bid < 4096) {                       // cast x: 4 floats/thread
    int i = bid * 256 + t;
    float4 v = ((const float4*)x)[i];
    ushort4 o;
    o.x = f2bf(v.x); o.y = f2bf(v.y); o.z = f2bf(v.z); o.w = f2bf(v.w);
    ((ushort4*)xb)[i] = o;
  } else if (bid < 6144) {                // W[h][i][o] f32 -> Wt[h][o][i] bf16
    int b2 = bid - 4096;
    int i0 = (b2 & 31) * 32, o0 = ((b2 >> 5) & 15) * 32, h = b2 >> 9;
    int tx = t & 31, ty = t >> 5;
#pragma unroll
    for (int r = 0; r < 32; r += 8)
      tile[ty + r][tx] = W[((size_t)(h * IND + i0 + ty + r)) * OUTD + o0 + tx];
    __syncthreads();
#pragma unroll
    for (int r = 0; r < 32; r += 8)
      Wt[((size_t)(h * OUTD + o0 + ty + r)) * IND + i0 + tx] = f2bf(tile[tx][ty + r]);
  } else {                                // edge pass A: dedup + per-(row,bucket) counts
    int e = (bid - 6144) * 256 + t;
    int row = ei[e], col = ei[EE + e];
    unsigned key = ((unsigned)row << 12) | (unsigned)col;
    unsigned bit = 1u << (key & 31);
    unsigned old = atomicOr(&bitmap[key >> 5], bit);
    if (old & bit) { flags[e] = 1; return; }   // duplicate (same e value -> any winner ok)
    flags[e] = 0;
    atomicAdd(&counts2[row * NBKT + (col >> BKT_SHIFT)], 1);
  }
}

// ---------------- K2: bf16 MFMA GEMM 128x128, BK=32, 4 blocks/CU + scan block -----------------
// LDS slot swizzle s = c ^ ((row>>1)&3): 8 consecutive rows hit 8 distinct 16B wrap positions
// -> 16 lanes = 2-way bank aliasing (free, m136). 32 KB LDS -> 4 blocks/CU (vs BK=64's 2).
__device__ __forceinline__ void gload16(const unsigned short* g, unsigned short* l) {
  __builtin_amdgcn_global_load_lds((const __attribute__((address_space(1))) void*)g,
                                   (__attribute__((address_space(3))) void*)l, 16, 0, 0);
}

__device__ void scan_block_256(const int* __restrict__ c2, int* __restrict__ off2,
                               int* __restrict__ cur2) {
  __shared__ int wtot[4];
  const int t = threadIdx.x, w = t >> 6, lane = t & 63;
  const int4* src = (const int4*)c2 + t * 32;   // 128 ints/thread, two-pass
  int s = 0;
  for (int k = 0; k < 32; k++) { int4 v = src[k]; s += v.x + v.y + v.z + v.w; }
  int inc = s;
#pragma unroll
  for (int d = 1; d < 64; d <<= 1) {
    int u = __shfl_up(inc, d);
    if (lane >= d) inc += u;
  }
  if (lane == 63) wtot[w] = inc;
  __syncthreads();
  int wpre = 0;
#pragma unroll
  for (int k = 0; k < 4; k++)
    if (k < w) wpre += wtot[k];
  int o = wpre + inc - s;                        // exclusive prefix of this thread's chunk
  if (t == 255) off2[NN * NBKT] = o + s;         // sentinel: total nondup count
  int4* od = (int4*)off2 + t * 32;
  int4* cd = (int4*)cur2 + t * 32;
  for (int k = 0; k < 32; k++) {
    int4 v = src[k];
    int4 ov;
    ov.x = o; o += v.x;
    ov.y = o; o += v.y;
    ov.z = o; o += v.z;
    ov.w = o; o += v.w;
    od[k] = ov;
    cd[k] = ov;
  }
}

__global__ __launch_bounds__(256, 4) void gemm_scan_kernel(
    const unsigned short* __restrict__ X, const unsigned short* __restrict__ Wt,
    const float* __restrict__ Av, unsigned char* __restrict__ Hb8,
    float* __restrict__ s4_src, float* __restrict__ s4_dst, float* __restrict__ Scol,
    const int* __restrict__ c2, int* __restrict__ off2, int* __restrict__ cur2) {
  if (blockIdx.x == 512) {   // the scan rides along, hidden under the GEMM
    scan_block_256(c2, off2, cur2);
    return;
  }
  __shared__ __align__(16) unsigned short As[2][4096];  // [128 rows][32 k] bf16, slot-swizzled
  __shared__ __align__(16) unsigned short Bs[2][4096];
  const int t = threadIdx.x, w = t >> 6, lane = t & 63;
  const int bx = blockIdx.x & 3, hh = (blockIdx.x >> 2) & 3, by = blockIdx.x >> 4;

  const unsigned short* Ab0 = X + (size_t)(by * 128) * IND;
  const unsigned short* Bb0 = Wt + (size_t)(hh * OUTD + bx * 128) * IND;

  // staging: seg in [0,512); row=seg>>2, LDS slot=seg&3, global granule c = slot ^ ((row>>1)&3)
  const int seg0 = w * 128 + lane, seg1 = w * 128 + 64 + lane;
  const int sr0 = seg0 >> 2, sc0 = (seg0 & 3) ^ ((sr0 >> 1) & 3);
  const int sr1 = seg1 >> 2, sc1 = (seg1 & 3) ^ ((sr1 >> 1) & 3);

  // fragment reads: lane (rlo,g) reads row ra, slot g^((ra>>1)&3)
  const int wr = w >> 1, wc = w & 1, g = lane >> 4, rlo = lane & 15;
  int aoff[4], boff[4];
#pragma unroll
  for (int i = 0; i < 4; i++) {
    int ra = wr * 64 + i * 16 + rlo;
    aoff[i] = ra * 64 + ((g ^ ((ra >> 1) & 3)) << 4);
    int rb = wc * 64 + i * 16 + rlo;
    boff[i] = rb * 64 + ((g ^ ((rb >> 1) & 3)) << 4);
  }

  f32x4 zero = {0.f, 0.f, 0.f, 0.f};
  f32x4 acc[4][4];
#pragma unroll
  for (int i = 0; i < 4; i++)
#pragma unroll
    for (int j = 0; j < 4; j++) acc[i][j] = zero;

#define STAGE(buf, kt)                                               \
  do {                                                               \
    const unsigned short* ga = Ab0 + (kt) * 32;                      \
    const unsigned short* gb = Bb0 + (kt) * 32;                      \
    gload16(ga + sr0 * IND + sc0 * 8, &As[buf][w * 1024]);           \
    gload16(ga + sr1 * IND + sc1 * 8, &As[buf][w * 1024 + 512]);     \
    gload16(gb + sr0 * IND + sc0 * 8, &Bs[buf][w * 1024]);           \
    gload16(gb + sr1 * IND + sc1 * 8, &Bs[buf][w * 1024 + 512]);     \
  } while (0)

  STAGE(0, 0);
  __syncthreads();
  int cur = 0;
  for (int kt = 0; kt < 32; ++kt) {
    if (kt != 31) STAGE(cur ^ 1, kt + 1);
    const char* Abuf = (const char*)As[cur];
    const char* Bbuf = (const char*)Bs[cur];
    bf16x8 av[4], bv[4];
#pragma unroll
    for (int i = 0; i < 4; i++) {
      av[i] = *(const bf16x8*)(Abuf + aoff[i]);
      bv[i] = *(const bf16x8*)(Bbuf + boff[i]);
    }
#pragma unroll
    for (int i = 0; i < 4; i++)
#pragma unroll
      for (int j = 0; j < 4; j++)
        acc[i][j] = __builtin_amdgcn_mfma_f32_16x16x32_bf16(av[i], bv[j], acc[i][j], 0, 0, 0);
    __syncthreads();
    cur ^= 1;
  }
#undef STAGE

  // ---- epilogue. C/D layout: col = lane&15 (rlo), row = (lane>>4)*4+q  [m89/m91 verified]
#pragma unroll
  for (int i = 0; i < 4; i++)
#pragma unroll
    for (int j = 0; j < 4; j++) {
      int mm0 = by * 128 + wr * 64 + i * 16 + g * 4;
      int nn = bx * 128 + wc * 64 + j * 16 + rlo;
#pragma unroll
      for (int q = 0; q < 4; q++) {
        int p = __builtin_amdgcn_cvt_pk_fp8_f32(acc[i][j][q], acc[i][j][q], 0, false);
        Hb8[((size_t)(mm0 + q) * NH + hh) * OUTD + nn] = (unsigned char)p;
      }
    }

  float as_[4], ad_[4];
#pragma unroll
  for (int j = 0; j < 4; j++) {
    int nn = bx * 128 + wc * 64 + j * 16 + rlo;
    as_[j] = Av[hh * 2 * OUTD + nn];
    ad_[j] = Av[hh * 2 * OUTD + OUTD + nn];
  }
#pragma unroll
  for (int i = 0; i < 4; i++)
#pragma unroll
    for (int q = 0; q < 4; q++) {
      float vs = 0.f, vd = 0.f;
#pragma unroll
      for (int j = 0; j < 4; j++) {
        float tv = acc[i][j][q];
        vs += tv * as_[j];
        vd += tv * ad_[j];
      }
#pragma unroll
      for (int m = 1; m < 16; m <<= 1) {
        vs += __shfl_xor(vs, m);
        vd += __shfl_xor(vd, m);
      }
      if (rlo == 0) {
        int r = by * 128 + wr * 64 + i * 16 + g * 4 + q;
        atomicAdd(&s4_src[r * NH + hh], vs);   // [node][head] layout for finalize gathers
        atomicAdd(&s4_dst[r * NH + hh], vd);
      }
    }

#pragma unroll
  for (int j = 0; j < 4; j++) {
    float cv = 0.f;
#pragma unroll
    for (int i = 0; i < 4; i++)
#pragma unroll
      for (int q = 0; q < 4; q++) cv += acc[i][j][q];
    cv += __shfl_xor(cv, 16);
    cv += __shfl_xor(cv, 32);
    if (g == 0) {
      int nn = bx * 128 + wc * 64 + j * 16 + rlo;
      atomicAdd(&Scol[hh * OUTD + nn], cv);
    }
  }
}

// ---------------- K6: edge pass B — pure bucketed CSR scatter (g computed in finalize) -------
__global__ void edge_b_kernel(const int* __restrict__ ei, const unsigned char* __restrict__ flags,
                              int* __restrict__ cursor2, int* __restrict__ csr_col) {
  int e = blockIdx.x * 256 + threadIdx.x;
  if (flags[e]) return;
  int row = ei[e], col = ei[EE + e];
  int pos = atomicAdd(&cursor2[row * NBKT + (col >> BKT_SHIFT)], 1);
  csr_col[pos] = col;
}

// ---------------- K7: finalize — wave w = head w; fp8 gather; g computed inline --------------
__global__ __launch_bounds__(256) void finalize_kernel(
    const unsigned char* __restrict__ Hb8,   // [node][head][out] fp8 e4m3
    const float* __restrict__ S, const float* __restrict__ s4_src,
    const float* __restrict__ s4_dst, const int* __restrict__ offsets2,
    const int* __restrict__ csr_col, float* __restrict__ out) {
  __shared__ int cols_s[64];
  __shared__ float g_s[4][64];
  const int i = blockIdx.x, t = threadIdx.x;
  const int w = t >> 6, lane = t & 63;   // wave w handles head w

  const float ssrc = s4_src[i * NH + w];
  float acc[8];
  {
    const float4* Sv = (const float4*)(S + w * OUTD + lane * 8);
    float4 s0 = Sv[0], s1 = Sv[1];
    acc[0] = s0.x; acc[1] = s0.y; acc[2] = s0.z; acc[3] = s0.w;
    acc[4] = s1.x; acc[5] = s1.y; acc[6] = s1.z; acc[7] = s1.w;
  }
  float gsum = 0.f;

  const int start = offsets2[i * NBKT];
  const int cnt = offsets2[(i + 1) * NBKT] - start;   // i=4095 hits the sentinel
  for (int base = 0; base < cnt; base += 64) {
    int nload = min(64, cnt - base);
    __syncthreads();
    if (w == 0) cols_s[lane] = (lane < nload) ? csr_col[start + base + lane] : 0;
    __syncthreads();
    {   // per-wave: compute this head's g for edge 'lane' (same math/order as old edge_b)
      float gg = 0.f;
      if (lane < nload) {
        float e0 = ssrc + s4_dst[cols_s[lane] * NH + w];
        e0 = e0 > 0.f ? e0 : 0.2f * e0;
        gg = expf(e0) - 1.0f;
      }
      g_s[w][lane] = gg;   // wave-local: written+read by wave w only (no barrier needed)
    }
#pragma unroll 4
    for (int k = 0; k < nload; k++) {
      int cc = cols_s[k];
      float gg = g_s[w][k];
      gsum += gg;
      uint2 u = *(const uint2*)(Hb8 + ((size_t)(cc * NH + w)) * OUTD + lane * 8);
      f32x2 p0 = __builtin_amdgcn_cvt_pk_f32_fp8(u.x, false);
      f32x2 p1 = __builtin_amdgcn_cvt_pk_f32_fp8(u.x, true);
      f32x2 p2 = __builtin_amdgcn_cvt_pk_f32_fp8(u.y, false);
      f32x2 p3 = __builtin_amdgcn_cvt_pk_f32_fp8(u.y, true);
      acc[0] += gg * p0[0];
      acc[1] += gg * p0[1];
      acc[2] += gg * p1[0];
      acc[3] += gg * p1[1];
      acc[4] += gg * p2[0];
      acc[5] += gg * p2[1];
      acc[6] += gg * p3[0];
      acc[7] += gg * p3[1];
    }
  }

  float inv = 1.0f / ((float)NN + gsum);   // D = N*exp(0) + sum(exp(e)-1); max-shift unnecessary
  float4 o0, o1;
  o0.x = acc[0] * inv; o0.y = acc[1] * inv; o0.z = acc[2] * inv; o0.w = acc[3] * inv;
  o1.x = acc[4] * inv; o1.y = acc[5] * inv; o1.z = acc[6] * inv; o1.w = acc[7] * inv;
  float* ob = out + (size_t)i * (NH * OUTD) + w * OUTD + lane * 8;
  ((float4*)ob)[0] = o0;
  ((float4*)ob)[1] = o1;
}

extern "C" void kernel_launch(void* const* d_in, const int* in_sizes, int n_in,
                              void* d_out, int out_size, void* d_ws, size_t ws_size,
                              hipStream_t stream) {
  const float* x = (const float*)d_in[0];
  const int* ei = (const int*)d_in[1];
  const float* W = (const float*)d_in[2];
  const float* a = (const float*)d_in[3];
  float* out = (float*)d_out;

  char* ws = (char*)d_ws;
  unsigned short* xb = (unsigned short*)(ws);                       // 8 MB
  unsigned short* wt = (unsigned short*)(ws + (8ull << 20));        // 4 MB
  unsigned char* Hb8 = (unsigned char*)(ws + (12ull << 20));        // 8 MB  [node][head][out] fp8
  // ---- single contiguous zeroed region: s4_src, s4_dst, Scol, counts2, bitmap ----
  char* zreg = ws + (20ull << 20);
  float* s4_src = (float*)(zreg);                                   // 64 KB [node][head]
  float* s4_dst = (float*)(zreg + 65536);                           // 64 KB [node][head]
  float* Scol = (float*)(zreg + 2 * 65536);                         // 8 KB
  int* counts2 = (int*)(zreg + 2 * 65536 + 8192);                   // 128 KB
  unsigned* bitmap = (unsigned*)(zreg + 2 * 65536 + 8192 + 131072); // 2 MB
  const size_t ZBYTES = 2 * 65536 + 8192 + 131072 + ((size_t)NN * NN / 8);
  // ---- non-zeroed scratch ----
  unsigned char* flags = (unsigned char*)(ws + (23ull << 20));      // 128 KB
  int* offsets2 = (int*)(ws + (23ull << 20) + 262144);              // 128 KB + 4 (sentinel)
  int* cursor2 = (int*)(ws + (23ull << 20) + 2 * 262144);           // 128 KB
  int* csr_col = (int*)(ws + (24ull << 20));                        // 512 KB   (25 MB total)

  hipMemsetAsync(zreg, 0, ZBYTES, stream);

  prep_edge_kernel<<<4096 + 2048 + 512, 256, 0, stream>>>(x, xb, W, wt, ei, bitmap, counts2,
                                                          flags);
  gemm_scan_kernel<<<513, 256, 0, stream>>>(xb, wt, a, Hb8, s4_src, s4_dst, Scol, counts2,
                                            offsets2, cursor2);
  edge_b_kernel<<<EE / 256, 256, 0, stream>>>(ei, flags, cursor2, csr_col);
  finalize_kernel<<<NN, 256, 0, stream>>>(Hb8, Scol, s4_src, s4_dst, offsets2, csr_col, out);
}